// Round 5
// baseline (3085.625 us; speedup 1.0000x reference)
//
#include <hip/hip_runtime.h>

#define NROWS 65536
typedef unsigned short u16;
typedef __attribute__((ext_vector_type(8))) short bf16x8;
typedef __attribute__((ext_vector_type(4))) float f32x4;

__device__ __forceinline__ u16 tobf(float v) {
    unsigned b = __float_as_uint(v);
    b += 0x7fffu + ((b >> 16) & 1u);          // RNE
    return (u16)(b >> 16);
}
__device__ __forceinline__ float frombf(u16 h) {
    return __uint_as_float(((unsigned)h) << 16);
}
__device__ __forceinline__ void split2(float v, u16& h, u16& l) {
    h = tobf(v);
    l = tobf(v - frombf(h));
}

// raw barrier: ds_writes made visible (lgkmcnt(0)) without draining vmcnt,
// so global prefetch loads stay in flight across the barrier (T3/T4 pattern).
__device__ __forceinline__ void bar_lgkm() {
    asm volatile("s_waitcnt lgkmcnt(0)" ::: "memory");
    __builtin_amdgcn_s_barrier();
    __builtin_amdgcn_sched_barrier(0);
}

// ---------------------------------------------------------------------------
// Weight prep: W[K][N] fp32 -> Wth[N][K], Wtl[N][K] bf16 (transposed + split).
// ---------------------------------------------------------------------------
__global__ __launch_bounds__(256)
void wsplit(const float* __restrict__ W, u16* __restrict__ Th, u16* __restrict__ Tl,
            int K, int N)
{
    __shared__ float Tt[32][65];
    const int t = threadIdx.x;
    const int nb = blockIdx.x * 32, kb = blockIdx.y * 64;
    #pragma unroll
    for (int j = 0; j < 2; ++j) {
        int fi = j * 256 + t;
        int kk = fi >> 3;
        int n4 = (fi & 7) * 4;
        float4 v = *(const float4*)&W[(size_t)(kb + kk) * N + nb + n4];
        Tt[n4 + 0][kk] = v.x; Tt[n4 + 1][kk] = v.y;
        Tt[n4 + 2][kk] = v.z; Tt[n4 + 3][kk] = v.w;
    }
    __syncthreads();
    #pragma unroll
    for (int j = 0; j < 2; ++j) {
        int oi = j * 256 + t;
        int n  = oi >> 4;
        int k4 = (oi & 15) * 4;
        ushort4 h, l;
        split2(Tt[n][k4 + 0], h.x, l.x); split2(Tt[n][k4 + 1], h.y, l.y);
        split2(Tt[n][k4 + 2], h.z, l.z); split2(Tt[n][k4 + 3], h.w, l.w);
        size_t oa = (size_t)(nb + n) * K + kb + k4;
        *(ushort4*)(Th + oa) = h;
        *(ushort4*)(Tl + oa) = l;
    }
}

// ---------------------------------------------------------------------------
// bf16x3-split MFMA GEMM, 2-phase pipeline:
//   - A fp32 -> split -> LDS, double-buffered, ONE raw barrier per BK=32 step;
//     next tile's global loads stay in flight across the barrier.
//   - B (pre-split bf16 [N][K]) frags read DIRECTLY from global (L2-resident
//     weights), issued before the A prefetch so MFMA waits vmcnt(N), not 0.
// Numerically identical to the R4 version (same values, same MFMA order).
// ---------------------------------------------------------------------------
template<int FM, int FN, int NWX, int NWY, int RELU>
__global__ __launch_bounds__(256)
void gemm3(const float* __restrict__ A1, int w1,
           const float* __restrict__ A2, int w2,
           const u16* __restrict__ Wth, const u16* __restrict__ Wtl,
           const float* __restrict__ bias,
           float* __restrict__ C, int Kin, int Nout)
{
    constexpr int BM = NWY * FM * 16;
    constexpr int BN = NWX * FN * 16;
    constexpr int LDT = 40;                 // u16 stride (80 B, 16B-aligned pad)
    constexpr int AIT = BM / 32;            // float4 A-loads per thread per tile
    static_assert(NWX * NWY == 4, "4 waves");
    __shared__ u16 Ah[2][BM * LDT], Al[2][BM * LDT];

    const int t = threadIdx.x, lane = t & 63, w = t >> 6;
    const int wx = w % NWX, wy = w / NWX;
    const int lg = lane >> 4, lm = lane & 15;
    const int rbase = blockIdx.y * BM, cbase = blockIdx.x * BN;

    f32x4 acc[FM][FN];
    #pragma unroll
    for (int i = 0; i < FM; ++i)
        #pragma unroll
        for (int j = 0; j < FN; ++j) acc[i][j] = (f32x4){0.f, 0.f, 0.f, 0.f};

    float4 av[AIT];

    auto loadA = [&](int kb) {
        #pragma unroll
        for (int j = 0; j < AIT; ++j) {
            int fi  = j * 256 + t;
            int row = fi >> 3;
            int k   = (fi & 7) * 4;
            int gc  = kb + k;
            const float* src = (gc < w1) ? (A1 + (size_t)(rbase + row) * w1 + gc)
                                         : (A2 + (size_t)(rbase + row) * w2 + (gc - w1));
            av[j] = *(const float4*)src;
        }
    };
    auto writeA = [&](int b) {
        #pragma unroll
        for (int j = 0; j < AIT; ++j) {
            int fi  = j * 256 + t;
            int row = fi >> 3;
            int k   = (fi & 7) * 4;
            ushort4 h, l;
            split2(av[j].x, h.x, l.x); split2(av[j].y, h.y, l.y);
            split2(av[j].z, h.z, l.z); split2(av[j].w, h.w, l.w);
            *(ushort4*)&Ah[b][row * LDT + k] = h;
            *(ushort4*)&Al[b][row * LDT + k] = l;
        }
    };

    loadA(0);
    writeA(0);
    bar_lgkm();

    const int NSTEP = Kin / 32;
    for (int ti = 0; ti < NSTEP; ++ti) {
        // B frags for this step, straight from global (issued first)
        bf16x8 b_h[FN], b_l[FN];
        #pragma unroll
        for (int fn = 0; fn < FN; ++fn) {
            size_t ga = (size_t)(cbase + wx * FN * 16 + fn * 16 + lm) * Kin + ti * 32 + lg * 8;
            b_h[fn] = *(const bf16x8*)(Wth + ga);
            b_l[fn] = *(const bf16x8*)(Wtl + ga);
        }
        // prefetch next A tile (stays in flight across the barrier below)
        if (ti + 1 < NSTEP) loadA((ti + 1) * 32);

        const int b = ti & 1;
        bf16x8 a_h[FM], a_l[FM];
        #pragma unroll
        for (int fm = 0; fm < FM; ++fm) {
            int off = (wy * FM * 16 + fm * 16 + lm) * LDT + lg * 8;
            a_h[fm] = *(const bf16x8*)&Ah[b][off];
            a_l[fm] = *(const bf16x8*)&Al[b][off];
        }
        #pragma unroll
        for (int fm = 0; fm < FM; ++fm)
            #pragma unroll
            for (int fn = 0; fn < FN; ++fn) {
                acc[fm][fn] = __builtin_amdgcn_mfma_f32_16x16x32_bf16(a_h[fm], b_h[fn], acc[fm][fn], 0, 0, 0);
                acc[fm][fn] = __builtin_amdgcn_mfma_f32_16x16x32_bf16(a_h[fm], b_l[fn], acc[fm][fn], 0, 0, 0);
                acc[fm][fn] = __builtin_amdgcn_mfma_f32_16x16x32_bf16(a_l[fm], b_h[fn], acc[fm][fn], 0, 0, 0);
            }

        if (ti + 1 < NSTEP) writeA((ti + 1) & 1);
        bar_lgkm();
    }

    float bn_[FN];
    #pragma unroll
    for (int fn = 0; fn < FN; ++fn)
        bn_[fn] = bias[cbase + wx * FN * 16 + fn * 16 + lm];
    #pragma unroll
    for (int fm = 0; fm < FM; ++fm)
        #pragma unroll
        for (int fn = 0; fn < FN; ++fn)
            #pragma unroll
            for (int r = 0; r < 4; ++r) {
                int m = rbase + wy * FM * 16 + fm * 16 + lg * 4 + r;
                int n = cbase + wx * FN * 16 + fn * 16 + lm;
                float v = acc[fm][fn][r] + bn_[fn];
                if (RELU) v = fmaxf(v, 0.f);
                C[(size_t)m * Nout + n] = v;
            }
}

// ---------------------------------------------------------------------------
__global__ __launch_bounds__(256)
void cbnorm_kernel(const float* __restrict__ cb, float* __restrict__ cbn)
{
    int code = blockIdx.x * 256 + threadIdx.x;      // 0..8191
    const float* p = cb + (size_t)code * 128;
    float s = 0.f;
    #pragma unroll 8
    for (int d4 = 0; d4 < 32; ++d4) {
        float4 v = *(const float4*)(p + d4 * 4);
        s += v.x * v.x + v.y * v.y + v.z * v.z + v.w * v.w;
    }
    cbn[code] = s;
}

// ---------------------------------------------------------------------------
__global__ __launch_bounds__(256)
void cbsplit(const float* __restrict__ cb, u16* __restrict__ CBh, u16* __restrict__ CBl)
{
    int i = (blockIdx.x * 256 + threadIdx.x) * 4;   // 1048576 elems / 4
    float4 v = *(const float4*)(cb + i);
    ushort4 h, l;
    split2(v.x, h.x, l.x); split2(v.y, h.y, l.y);
    split2(v.z, h.z, l.z); split2(v.w, h.w, l.w);
    *(ushort4*)(CBh + i) = h;
    *(ushort4*)(CBl + i) = l;
}

// ---------------------------------------------------------------------------
// MFMA residual VQ (transposed distance GEMM, lane-local argmin fold,
// top-2 + exact fp32 recheck when gap <= EPS). v2: no launch-bounds cap,
// cbn read from global (LDS 38.1 KB -> 3-4 blocks/CU), setprio around MFMA.
// ---------------------------------------------------------------------------
#define RVQ_EPS 4e-3f

__device__ __forceinline__ float dot128(const float* __restrict__ r,
                                        const float* __restrict__ c)
{
    float s = 0.f;
    #pragma unroll 8
    for (int i = 0; i < 32; ++i) {
        float4 a = *(const float4*)(r + i * 4);
        float4 b = *(const float4*)(c + i * 4);
        s += a.x * b.x + a.y * b.y + a.z * b.z + a.w * b.w;
    }
    return s;
}

__global__ __launch_bounds__(256)
void rvq_mfma(float* __restrict__ z, const float* __restrict__ zp,
              const float* __restrict__ cbf,
              const u16* __restrict__ CBh, const u16* __restrict__ CBl,
              const float* __restrict__ cbn,
              float* __restrict__ zhat /* aliases z */)
{
    __shared__ float r_lds[64 * 132];
    __shared__ float red_m1[256];   // [w][nt][lm]
    __shared__ int   red_k1[256];
    __shared__ float red_m2[256];
    __shared__ int   red_k2[256];
    __shared__ int   idx_sh[64];

    const int t = threadIdx.x, lane = t & 63, w = t >> 6;
    const int lm = lane & 15, lg = lane >> 4;
    const int rbase = blockIdx.x * 64;

    // r = z - zp
    #pragma unroll
    for (int jj = 0; jj < 8; ++jj) {
        int f   = t + 256 * jj;
        int row = f >> 5;
        int c4  = (f & 31) << 2;
        float4 zv = *(const float4*)(z  + (size_t)(rbase + row) * 128 + c4);
        float4 pv = *(const float4*)(zp + (size_t)(rbase + row) * 128 + c4);
        float4 rv = make_float4(zv.x - pv.x, zv.y - pv.y, zv.z - pv.z, zv.w - pv.w);
        *(float4*)&r_lds[row * 132 + c4] = rv;
    }
    __syncthreads();

    for (int q = 0; q < 8; ++q) {
        // split r fragments into regs (r_lds stable here)
        bf16x8 rh[4][4], rl[4][4];
        #pragma unroll
        for (int nt = 0; nt < 4; ++nt)
            #pragma unroll
            for (int ks = 0; ks < 4; ++ks) {
                const float* rp = &r_lds[(nt * 16 + lm) * 132 + ks * 32 + lg * 8];
                float4 v0 = *(const float4*)rp;
                float4 v1 = *(const float4*)(rp + 4);
                float fv[8] = { v0.x, v0.y, v0.z, v0.w, v1.x, v1.y, v1.z, v1.w };
                bf16x8 hh, ll;
                #pragma unroll
                for (int j = 0; j < 8; ++j) {
                    u16 h, l;
                    split2(fv[j], h, l);
                    hh[j] = (short)h; ll[j] = (short)l;
                }
                rh[nt][ks] = hh; rl[nt][ks] = ll;
            }

        float m1[4], m2v[4];
        int   k1[4], k2[4];
        #pragma unroll
        for (int nt = 0; nt < 4; ++nt) { m1[nt] = 3.4e38f; m2v[nt] = 3.4e38f; k1[nt] = 0; k2[nt] = 0; }

        const int klo = w * 16 + lg * 4;
        for (int c = 0; c < 16; ++c) {
            int cb0 = c * 64 + w * 16;
            bf16x8 ah[4], al[4];
            size_t gb = ((size_t)q * 1024 + cb0 + lm) * 128 + lg * 8;
            #pragma unroll
            for (int ks = 0; ks < 4; ++ks) {
                ah[ks] = *(const bf16x8*)(CBh + gb + ks * 32);
                al[ks] = *(const bf16x8*)(CBl + gb + ks * 32);
            }
            float4 cbn4 = *(const float4*)(cbn + q * 1024 + cb0 + lg * 4);

            #pragma unroll
            for (int nt = 0; nt < 4; ++nt) {
                f32x4 acc = (f32x4){0.f, 0.f, 0.f, 0.f};
                __builtin_amdgcn_s_setprio(1);
                #pragma unroll
                for (int ks = 0; ks < 4; ++ks) {
                    acc = __builtin_amdgcn_mfma_f32_16x16x32_bf16(ah[ks], rh[nt][ks], acc, 0, 0, 0);
                    acc = __builtin_amdgcn_mfma_f32_16x16x32_bf16(ah[ks], rl[nt][ks], acc, 0, 0, 0);
                    acc = __builtin_amdgcn_mfma_f32_16x16x32_bf16(al[ks], rh[nt][ks], acc, 0, 0, 0);
                }
                __builtin_amdgcn_s_setprio(0);
                float cbn_a[4] = { cbn4.x, cbn4.y, cbn4.z, cbn4.w };
                #pragma unroll
                for (int r = 0; r < 4; ++r) {
                    float d = fmaf(-2.f, acc[r], cbn_a[r]);
                    int  kk = c * 64 + klo + r;
                    bool lt1 = d < m1[nt];
                    bool lt2 = d < m2v[nt];
                    float nm2 = lt1 ? m1[nt] : (lt2 ? d : m2v[nt]);
                    int   nk2 = lt1 ? k1[nt] : (lt2 ? kk : k2[nt]);
                    if (lt1) { m1[nt] = d; k1[nt] = kk; }
                    m2v[nt] = nm2; k2[nt] = nk2;
                }
            }
        }

        // in-wave reduce across lg groups (xor 16, 32)
        #pragma unroll
        for (int nt = 0; nt < 4; ++nt) {
            #pragma unroll
            for (int st = 0; st < 2; ++st) {
                int msk = 16 << st;
                float om1 = __shfl_xor(m1[nt], msk);
                int   ok1 = __shfl_xor(k1[nt], msk);
                float om2 = __shfl_xor(m2v[nt], msk);
                int   ok2 = __shfl_xor(k2[nt], msk);
                bool aw = (m1[nt] < om1) || (m1[nt] == om1 && k1[nt] < ok1);
                float w1 = aw ? m1[nt] : om1;  int wk1 = aw ? k1[nt] : ok1;
                float l1 = aw ? om1 : m1[nt];  int lk1 = aw ? ok1 : k1[nt];
                float s2 = aw ? m2v[nt] : om2; int sk2 = aw ? k2[nt] : ok2;
                if (l1 < s2 || (l1 == s2 && lk1 < sk2)) { s2 = l1; sk2 = lk1; }
                m1[nt] = w1; k1[nt] = wk1; m2v[nt] = s2; k2[nt] = sk2;
            }
        }
        if (lane < 16) {
            #pragma unroll
            for (int nt = 0; nt < 4; ++nt) {
                int o = w * 64 + nt * 16 + lm;
                red_m1[o] = m1[nt]; red_k1[o] = k1[nt];
                red_m2[o] = m2v[nt]; red_k2[o] = k2[nt];
            }
        }
        __syncthreads();

        if (t < 64) {
            float M1 = 3.4e38f, M2 = 3.4e38f;
            int   K1 = 0x7fffffff, K2 = 0x7fffffff;
            #pragma unroll
            for (int ww = 0; ww < 4; ++ww) {
                int o = ww * 64 + t;
                float a1 = red_m1[o]; int b1 = red_k1[o];
                float a2 = red_m2[o]; int b2 = red_k2[o];
                if (a1 < M1 || (a1 == M1 && b1 < K1)) {
                    M2 = M1; K2 = K1; M1 = a1; K1 = b1;
                } else if (a1 < M2 || (a1 == M2 && b1 < K2)) { M2 = a1; K2 = b1; }
                if (a2 < M2 || (a2 == M2 && b2 < K2)) { M2 = a2; K2 = b2; }
            }
            int pick = K1;
            if (M2 - M1 <= RVQ_EPS) {
                const float* rrow = &r_lds[t * 132];
                float d1 = cbn[q * 1024 + K1] - 2.f * dot128(rrow, cbf + ((size_t)q * 1024 + K1) * 128);
                float d2 = cbn[q * 1024 + K2] - 2.f * dot128(rrow, cbf + ((size_t)q * 1024 + K2) * 128);
                if (d2 < d1 || (d2 == d1 && K2 < K1)) pick = K2;
            }
            idx_sh[t] = pick;
        }
        __syncthreads();

        // r -= cbf[q][idx]  (exact fp32)
        #pragma unroll
        for (int jj = 0; jj < 8; ++jj) {
            int f   = t + 256 * jj;
            int row = f >> 5;
            int c4  = (f & 31) << 2;
            int k   = idx_sh[row];
            float4 v = *(const float4*)(cbf + ((size_t)q * 1024 + k) * 128 + c4);
            float4* rp = (float4*)&r_lds[row * 132 + c4];
            float4 rv = *rp;
            rv.x -= v.x; rv.y -= v.y; rv.z -= v.z; rv.w -= v.w;
            *rp = rv;
        }
        __syncthreads();
    }

    // zhat = z - r_final (in place)
    #pragma unroll
    for (int jj = 0; jj < 8; ++jj) {
        int f   = t + 256 * jj;
        int row = f >> 5;
        int c4  = (f & 31) << 2;
        float4 zv = *(const float4*)(z + (size_t)(rbase + row) * 128 + c4);
        float4 rv = *(float4*)&r_lds[row * 132 + c4];
        float4 o = make_float4(zv.x - rv.x, zv.y - rv.y, zv.z - rv.z, zv.w - rv.w);
        *(float4*)(zhat + (size_t)(rbase + row) * 128 + c4) = o;
    }
}

// ---------------------------------------------------------------------------
extern "C" void kernel_launch(void* const* d_in, const int* in_sizes, int n_in,
                              void* d_out, int out_size, void* d_ws, size_t ws_size,
                              hipStream_t stream)
{
    const float* s    = (const float*)d_in[0];
    const float* goal = (const float*)d_in[1];
    const float* Wp[9]  = { (const float*)d_in[2],  (const float*)d_in[4],  (const float*)d_in[6],
                            (const float*)d_in[8],  (const float*)d_in[10], (const float*)d_in[12],
                            (const float*)d_in[14], (const float*)d_in[16], (const float*)d_in[18] };
    const float* Bp[9]  = { (const float*)d_in[3],  (const float*)d_in[5],  (const float*)d_in[7],
                            (const float*)d_in[9],  (const float*)d_in[11], (const float*)d_in[13],
                            (const float*)d_in[15], (const float*)d_in[17], (const float*)d_in[19] };
    const float* cb   = (const float*)d_in[20];
    float* out = (float*)d_out;

    static const int WK[9] = { 256, 512, 512, 384, 512, 512, 384, 1024, 1024 };
    static const int WN[9] = { 512, 512, 128, 512, 512, 128, 1024, 1024, 32 };
    size_t woff[10]; woff[0] = 0;
    for (int i = 0; i < 9; ++i) woff[i + 1] = woff[i] + (size_t)WK[i] * WN[i]; // 2457600

    float* zp  = (float*)d_ws;                       // [N,128]
    float* zz  = zp + (size_t)NROWS * 128;           // [N,128]; zhat in-place
    float* cbn = zz + (size_t)NROWS * 128;           // [8192]
    u16*  Wth  = (u16*)(cbn + 8192);
    u16*  Wtl  = Wth + woff[9];
    u16*  CBh  = Wtl + woff[9];                      // [1048576]
    u16*  CBl  = CBh + 1048576;
    uintptr_t bA = ((uintptr_t)(CBl + 1048576) + 255) & ~(uintptr_t)255;
    float* bufA = (float*)bA;

    size_t used = (size_t)(bA - (uintptr_t)d_ws);
    size_t avail = (ws_size > used) ? (ws_size - used) : 0;
    size_t ch = avail / (2 * 1024 * sizeof(float));
    if (ch > NROWS) ch = NROWS;
    ch &= ~(size_t)127;
    if (ch < 128) ch = 128;
    const int CH = (int)ch;
    float* bufB = bufA + (size_t)CH * 1024;

    dim3 blk(256);

    cbnorm_kernel<<<32, blk, 0, stream>>>(cb, cbn);
    cbsplit<<<1024, blk, 0, stream>>>(cb, CBh, CBl);
    for (int i = 0; i < 9; ++i)
        wsplit<<<dim3(WN[i] / 32, WK[i] / 64), blk, 0, stream>>>(Wp[i], Wth + woff[i], Wtl + woff[i], WK[i], WN[i]);

    // prior + posterior, chunked
    for (int off = 0; off < NROWS; off += CH) {
        int rows = (NROWS - off) < CH ? (NROWS - off) : CH;
        int gy = rows / 128;
        const float* sC = s + (size_t)off * 256;
        const float* gC = goal + (size_t)off * 128;
        gemm3<4,4,2,2,1><<<dim3(4, gy), blk, 0, stream>>>(sC, 256, nullptr, 0, Wth + woff[0], Wtl + woff[0], Bp[0], bufA, 256, 512);
        gemm3<4,4,2,2,1><<<dim3(4, gy), blk, 0, stream>>>(bufA, 512, nullptr, 0, Wth + woff[1], Wtl + woff[1], Bp[1], bufB, 512, 512);
        gemm3<4,4,2,2,0><<<dim3(1, gy), blk, 0, stream>>>(bufB, 512, nullptr, 0, Wth + woff[2], Wtl + woff[2], Bp[2], zp + (size_t)off * 128, 512, 128);
        gemm3<4,4,2,2,1><<<dim3(4, gy), blk, 0, stream>>>(sC, 256, gC, 128, Wth + woff[3], Wtl + woff[3], Bp[3], bufA, 384, 512);
        gemm3<4,4,2,2,1><<<dim3(4, gy), blk, 0, stream>>>(bufA, 512, nullptr, 0, Wth + woff[4], Wtl + woff[4], Bp[4], bufB, 512, 512);
        gemm3<4,4,2,2,0><<<dim3(1, gy), blk, 0, stream>>>(bufB, 512, nullptr, 0, Wth + woff[5], Wtl + woff[5], Bp[5], zz + (size_t)off * 128, 512, 128);
    }

    rvq_mfma<<<NROWS / 64, blk, 0, stream>>>(zz, zp, cb, CBh, CBl, cbn, zz);

    // decoder, chunked
    for (int off = 0; off < NROWS; off += CH) {
        int rows = (NROWS - off) < CH ? (NROWS - off) : CH;
        int gy = rows / 128;
        const float* sC = s + (size_t)off * 256;
        const float* zC = zz + (size_t)off * 128;
        gemm3<4,4,2,2,1><<<dim3(8, gy), blk, 0, stream>>>(sC, 256, zC, 128, Wth + woff[6], Wtl + woff[6], Bp[6], bufA, 384, 1024);
        gemm3<4,4,2,2,1><<<dim3(8, gy), blk, 0, stream>>>(bufA, 1024, nullptr, 0, Wth + woff[7], Wtl + woff[7], Bp[7], bufB, 1024, 1024);
        gemm3<2,2,1,4,0><<<dim3(1, gy), blk, 0, stream>>>(bufB, 1024, nullptr, 0, Wth + woff[8], Wtl + woff[8], Bp[8], out + (size_t)off * 32, 1024, 32);
    }
}

// Round 6
// 2953.510 us; speedup vs baseline: 1.0447x; 1.0447x over previous
//
#include <hip/hip_runtime.h>

#define NROWS 65536
typedef unsigned short u16;
typedef __attribute__((ext_vector_type(8))) short bf16x8;
typedef __attribute__((ext_vector_type(4))) float f32x4;

__device__ __forceinline__ u16 tobf(float v) {
    unsigned b = __float_as_uint(v);
    b += 0x7fffu + ((b >> 16) & 1u);          // RNE
    return (u16)(b >> 16);
}
__device__ __forceinline__ float frombf(u16 h) {
    return __uint_as_float(((unsigned)h) << 16);
}
__device__ __forceinline__ void split2(float v, u16& h, u16& l) {
    h = tobf(v);
    l = tobf(v - frombf(h));
}

// ---------------------------------------------------------------------------
// Weight prep: W[K][N] fp32 -> Wth[N][K], Wtl[N][K] bf16 (transposed + split).
// ---------------------------------------------------------------------------
__global__ __launch_bounds__(256)
void wsplit(const float* __restrict__ W, u16* __restrict__ Th, u16* __restrict__ Tl,
            int K, int N)
{
    __shared__ float Tt[32][65];
    const int t = threadIdx.x;
    const int nb = blockIdx.x * 32, kb = blockIdx.y * 64;
    #pragma unroll
    for (int j = 0; j < 2; ++j) {
        int fi = j * 256 + t;
        int kk = fi >> 3;
        int n4 = (fi & 7) * 4;
        float4 v = *(const float4*)&W[(size_t)(kb + kk) * N + nb + n4];
        Tt[n4 + 0][kk] = v.x; Tt[n4 + 1][kk] = v.y;
        Tt[n4 + 2][kk] = v.z; Tt[n4 + 3][kk] = v.w;
    }
    __syncthreads();
    #pragma unroll
    for (int j = 0; j < 2; ++j) {
        int oi = j * 256 + t;
        int n  = oi >> 4;
        int k4 = (oi & 15) * 4;
        ushort4 h, l;
        split2(Tt[n][k4 + 0], h.x, l.x); split2(Tt[n][k4 + 1], h.y, l.y);
        split2(Tt[n][k4 + 2], h.z, l.z); split2(Tt[n][k4 + 3], h.w, l.w);
        size_t oa = (size_t)(nb + n) * K + kb + k4;
        *(ushort4*)(Th + oa) = h;
        *(ushort4*)(Tl + oa) = l;
    }
}

// ---------------------------------------------------------------------------
// bf16x3-split MFMA GEMM (R4-proven version): both operands LDS-staged,
// LDT=40 pad, 2 barriers per BK=32 step.
// ---------------------------------------------------------------------------
template<int FM, int FN, int NWX, int NWY, int RELU>
__global__ __launch_bounds__(256)
void gemm3(const float* __restrict__ A1, int w1,
           const float* __restrict__ A2, int w2,
           const u16* __restrict__ Wth, const u16* __restrict__ Wtl,
           const float* __restrict__ bias,
           float* __restrict__ C, int Kin, int Nout)
{
    constexpr int BM = NWY * FM * 16;
    constexpr int BN = NWX * FN * 16;
    constexpr int LDT = 40;                   // padded (u16) stride
    static_assert(NWX * NWY == 4, "4 waves");
    __shared__ u16 Ah[BM * LDT], Al[BM * LDT], Bh[BN * LDT], Bl[BN * LDT];

    const int t = threadIdx.x, lane = t & 63, w = t >> 6;
    const int wx = w % NWX, wy = w / NWX;
    const int lg = lane >> 4, lm = lane & 15;
    const int rbase = blockIdx.y * BM, cbase = blockIdx.x * BN;

    f32x4 acc[FM][FN];
    #pragma unroll
    for (int i = 0; i < FM; ++i)
        #pragma unroll
        for (int j = 0; j < FN; ++j) acc[i][j] = (f32x4){0.f, 0.f, 0.f, 0.f};

    for (int kb = 0; kb < Kin; kb += 32) {
        #pragma unroll
        for (int j = 0; j < BM / 32; ++j) {
            int fi  = j * 256 + t;
            int row = fi >> 3;
            int k   = (fi & 7) * 4;
            int gc  = kb + k;
            const float* src = (gc < w1) ? (A1 + (size_t)(rbase + row) * w1 + gc)
                                         : (A2 + (size_t)(rbase + row) * w2 + (gc - w1));
            float4 v = *(const float4*)src;
            ushort4 h, l;
            split2(v.x, h.x, l.x); split2(v.y, h.y, l.y);
            split2(v.z, h.z, l.z); split2(v.w, h.w, l.w);
            *(ushort4*)&Ah[row * LDT + k] = h;
            *(ushort4*)&Al[row * LDT + k] = l;
        }
        #pragma unroll
        for (int j = 0; j < BN / 32; ++j) {
            int fi   = j * 256 + t;
            int nrow = fi >> 3;
            int k    = (fi & 7) * 4;
            size_t ga = (size_t)(cbase + nrow) * Kin + kb + k;
            *(ushort4*)&Bh[nrow * LDT + k] = *(const ushort4*)(Wth + ga);
            *(ushort4*)&Bl[nrow * LDT + k] = *(const ushort4*)(Wtl + ga);
        }
        __syncthreads();

        bf16x8 a_h[FM], a_l[FM], b_h[FN], b_l[FN];
        #pragma unroll
        for (int fm = 0; fm < FM; ++fm) {
            int off = (wy * FM * 16 + fm * 16 + lm) * LDT + lg * 8;
            a_h[fm] = *(const bf16x8*)&Ah[off];
            a_l[fm] = *(const bf16x8*)&Al[off];
        }
        #pragma unroll
        for (int fn = 0; fn < FN; ++fn) {
            int off = (wx * FN * 16 + fn * 16 + lm) * LDT + lg * 8;
            b_h[fn] = *(const bf16x8*)&Bh[off];
            b_l[fn] = *(const bf16x8*)&Bl[off];
        }
        #pragma unroll
        for (int fm = 0; fm < FM; ++fm)
            #pragma unroll
            for (int fn = 0; fn < FN; ++fn) {
                acc[fm][fn] = __builtin_amdgcn_mfma_f32_16x16x32_bf16(a_h[fm], b_h[fn], acc[fm][fn], 0, 0, 0);
                acc[fm][fn] = __builtin_amdgcn_mfma_f32_16x16x32_bf16(a_h[fm], b_l[fn], acc[fm][fn], 0, 0, 0);
                acc[fm][fn] = __builtin_amdgcn_mfma_f32_16x16x32_bf16(a_l[fm], b_h[fn], acc[fm][fn], 0, 0, 0);
            }
        __syncthreads();
    }

    float bn_[FN];
    #pragma unroll
    for (int fn = 0; fn < FN; ++fn)
        bn_[fn] = bias[cbase + wx * FN * 16 + fn * 16 + lm];
    #pragma unroll
    for (int fm = 0; fm < FM; ++fm)
        #pragma unroll
        for (int fn = 0; fn < FN; ++fn)
            #pragma unroll
            for (int r = 0; r < 4; ++r) {
                int m = rbase + wy * FM * 16 + fm * 16 + lg * 4 + r;
                int n = cbase + wx * FN * 16 + fn * 16 + lm;
                float v = acc[fm][fn][r] + bn_[fn];
                if (RELU) v = fmaxf(v, 0.f);
                C[(size_t)m * Nout + n] = v;
            }
}

// ---------------------------------------------------------------------------
__global__ __launch_bounds__(256)
void cbnorm_kernel(const float* __restrict__ cb, float* __restrict__ cbn)
{
    int code = blockIdx.x * 256 + threadIdx.x;      // 0..8191
    const float* p = cb + (size_t)code * 128;
    float s = 0.f;
    #pragma unroll 8
    for (int d4 = 0; d4 < 32; ++d4) {
        float4 v = *(const float4*)(p + d4 * 4);
        s += v.x * v.x + v.y * v.y + v.z * v.z + v.w * v.w;
    }
    cbn[code] = s;
}

// ---------------------------------------------------------------------------
__global__ __launch_bounds__(256)
void cbsplit(const float* __restrict__ cb, u16* __restrict__ CBh, u16* __restrict__ CBl)
{
    int i = (blockIdx.x * 256 + threadIdx.x) * 4;   // 1048576 elems / 4
    float4 v = *(const float4*)(cb + i);
    ushort4 h, l;
    split2(v.x, h.x, l.x); split2(v.y, h.y, l.y);
    split2(v.z, h.z, l.z); split2(v.w, h.w, l.w);
    *(ushort4*)(CBh + i) = h;
    *(ushort4*)(CBl + i) = l;
}

// ---------------------------------------------------------------------------
// MFMA residual VQ v3. 32 rows/block (2048 blocks), 4 waves.
//  - r fp32 in LDS (exact chain) + frag-major PRE-SPLIT hi/lo LDS buffer:
//    chunk((nt,ks,lg,lm)) = ((nt*4+ks)*4+lg)*16+lm; wave frag load is
//    ds_read_b128 at chunk*16B = base + lane*16 -> linear, conflict-free.
//  - fragments = 2nt x 4ks x hi/lo = 64 VGPRs -> fits 128-VGPR budget
//    (__launch_bounds__(256,4)) => 4 blocks/CU, 16 waves/CU.
//  - CB hi/lo frags from global (L2-resident).
//  - top-2 screen + exact fp32 recheck when gap <= EPS (argmin fp32-true).
// ---------------------------------------------------------------------------
#define RVQ_EPS 4e-3f

__device__ __forceinline__ float dot128(const float* __restrict__ r,
                                        const float* __restrict__ c)
{
    float s = 0.f;
    #pragma unroll 8
    for (int i = 0; i < 32; ++i) {
        float4 a = *(const float4*)(r + i * 4);
        float4 b = *(const float4*)(c + i * 4);
        s += a.x * b.x + a.y * b.y + a.z * b.z + a.w * b.w;
    }
    return s;
}

__global__ __launch_bounds__(256, 4)
void rvq_mfma(float* __restrict__ z, const float* __restrict__ zp,
              const float* __restrict__ cbf,
              const u16* __restrict__ CBh, const u16* __restrict__ CBl,
              const float* __restrict__ cbn,
              float* __restrict__ zhat /* aliases z */)
{
    __shared__ float r_lds[32 * 132];     // fp32 residual
    __shared__ u16   fh[512 * 8];         // frag-major bf16 hi
    __shared__ u16   fl[512 * 8];         // frag-major bf16 lo
    __shared__ float red_m1[128], red_m2[128];
    __shared__ int   red_k1[128], red_k2[128];
    __shared__ int   idx_sh[32];

    const int t = threadIdx.x, lane = t & 63, w = t >> 6;
    const int lm = lane & 15, lg = lane >> 4;
    const int rbase = blockIdx.x * 32;

    // ---- init: r = z - zp (coalesced)
    #pragma unroll
    for (int jj = 0; jj < 4; ++jj) {
        int f   = t + 256 * jj;           // 0..1023
        int row = f >> 5;                 // 0..31
        int c4  = (f & 31) << 2;          // 0..124
        float4 zv = *(const float4*)(z  + (size_t)(rbase + row) * 128 + c4);
        float4 pv = *(const float4*)(zp + (size_t)(rbase + row) * 128 + c4);
        float4 rv = make_float4(zv.x - pv.x, zv.y - pv.y, zv.z - pv.z, zv.w - pv.w);
        *(float4*)&r_lds[row * 132 + c4] = rv;
    }
    __syncthreads();
    // ---- init split -> frag buffer (row-fast mapping)
    #pragma unroll
    for (int jj = 0; jj < 4; ++jj) {
        int f   = t + 256 * jj;
        int row = f & 31;
        int c4  = (f >> 5) << 2;          // 0..124
        float4 rv = *(float4*)&r_lds[row * 132 + c4];
        int nt = row >> 4, lmr = row & 15;
        int ks = c4 >> 5, lgr = (c4 >> 3) & 3, off = c4 & 7;
        int chunk = ((nt * 4 + ks) * 4 + lgr) * 16 + lmr;
        ushort4 h, l;
        split2(rv.x, h.x, l.x); split2(rv.y, h.y, l.y);
        split2(rv.z, h.z, l.z); split2(rv.w, h.w, l.w);
        *(ushort4*)&fh[chunk * 8 + off] = h;
        *(ushort4*)&fl[chunk * 8 + off] = l;
    }
    __syncthreads();

    for (int q = 0; q < 8; ++q) {
        // ---- load r fragments once (linear ds_read_b128, conflict-free)
        bf16x8 rhf[2][4], rlf[2][4];
        #pragma unroll
        for (int nt = 0; nt < 2; ++nt)
            #pragma unroll
            for (int ks = 0; ks < 4; ++ks) {
                int chunk = (nt * 4 + ks) * 64 + lane;
                rhf[nt][ks] = *(const bf16x8*)&fh[chunk * 8];
                rlf[nt][ks] = *(const bf16x8*)&fl[chunk * 8];
            }

        float m1[2], m2v[2];
        int   k1[2], k2[2];
        #pragma unroll
        for (int nt = 0; nt < 2; ++nt) { m1[nt] = 3.4e38f; m2v[nt] = 3.4e38f; k1[nt] = 0; k2[nt] = 0; }

        const int klo = w * 16 + lg * 4;
        for (int c = 0; c < 16; ++c) {
            int cb0 = c * 64 + w * 16;
            size_t gb = ((size_t)q * 1024 + cb0 + lm) * 128;
            float4 cbn4 = *(const float4*)(cbn + q * 1024 + cb0 + lg * 4);

            f32x4 acc0 = (f32x4){0.f, 0.f, 0.f, 0.f};
            f32x4 acc1 = (f32x4){0.f, 0.f, 0.f, 0.f};
            #pragma unroll
            for (int ks = 0; ks < 4; ++ks) {
                bf16x8 ah = *(const bf16x8*)(CBh + gb + ks * 32 + lg * 8);
                bf16x8 al = *(const bf16x8*)(CBl + gb + ks * 32 + lg * 8);
                acc0 = __builtin_amdgcn_mfma_f32_16x16x32_bf16(ah, rhf[0][ks], acc0, 0, 0, 0);
                acc0 = __builtin_amdgcn_mfma_f32_16x16x32_bf16(ah, rlf[0][ks], acc0, 0, 0, 0);
                acc0 = __builtin_amdgcn_mfma_f32_16x16x32_bf16(al, rhf[0][ks], acc0, 0, 0, 0);
                acc1 = __builtin_amdgcn_mfma_f32_16x16x32_bf16(ah, rhf[1][ks], acc1, 0, 0, 0);
                acc1 = __builtin_amdgcn_mfma_f32_16x16x32_bf16(ah, rlf[1][ks], acc1, 0, 0, 0);
                acc1 = __builtin_amdgcn_mfma_f32_16x16x32_bf16(al, rhf[1][ks], acc1, 0, 0, 0);
            }
            float cbn_a[4] = { cbn4.x, cbn4.y, cbn4.z, cbn4.w };
            #pragma unroll
            for (int r = 0; r < 4; ++r) {
                int kk = c * 64 + klo + r;
                {   // nt = 0
                    float d = fmaf(-2.f, acc0[r], cbn_a[r]);
                    bool lt1 = d < m1[0];
                    bool lt2 = d < m2v[0];
                    float nm2 = lt1 ? m1[0] : (lt2 ? d : m2v[0]);
                    int   nk2 = lt1 ? k1[0] : (lt2 ? kk : k2[0]);
                    if (lt1) { m1[0] = d; k1[0] = kk; }
                    m2v[0] = nm2; k2[0] = nk2;
                }
                {   // nt = 1
                    float d = fmaf(-2.f, acc1[r], cbn_a[r]);
                    bool lt1 = d < m1[1];
                    bool lt2 = d < m2v[1];
                    float nm2 = lt1 ? m1[1] : (lt2 ? d : m2v[1]);
                    int   nk2 = lt1 ? k1[1] : (lt2 ? kk : k2[1]);
                    if (lt1) { m1[1] = d; k1[1] = kk; }
                    m2v[1] = nm2; k2[1] = nk2;
                }
            }
        }

        // ---- in-wave reduce across lg groups (xor 16, 32)
        #pragma unroll
        for (int nt = 0; nt < 2; ++nt) {
            #pragma unroll
            for (int st = 0; st < 2; ++st) {
                int msk = 16 << st;
                float om1 = __shfl_xor(m1[nt], msk);
                int   ok1 = __shfl_xor(k1[nt], msk);
                float om2 = __shfl_xor(m2v[nt], msk);
                int   ok2 = __shfl_xor(k2[nt], msk);
                bool aw = (m1[nt] < om1) || (m1[nt] == om1 && k1[nt] < ok1);
                float w1 = aw ? m1[nt] : om1;  int wk1 = aw ? k1[nt] : ok1;
                float l1 = aw ? om1 : m1[nt];  int lk1 = aw ? ok1 : k1[nt];
                float s2 = aw ? m2v[nt] : om2; int sk2 = aw ? k2[nt] : ok2;
                if (l1 < s2 || (l1 == s2 && lk1 < sk2)) { s2 = l1; sk2 = lk1; }
                m1[nt] = w1; k1[nt] = wk1; m2v[nt] = s2; k2[nt] = sk2;
            }
        }
        if (lane < 16) {
            #pragma unroll
            for (int nt = 0; nt < 2; ++nt) {
                int o = w * 32 + nt * 16 + lm;
                red_m1[o] = m1[nt]; red_k1[o] = k1[nt];
                red_m2[o] = m2v[nt]; red_k2[o] = k2[nt];
            }
        }
        __syncthreads();

        if (t < 32) {
            float M1 = 3.4e38f, M2 = 3.4e38f;
            int   K1 = 0x7fffffff, K2 = 0x7fffffff;
            #pragma unroll
            for (int ww = 0; ww < 4; ++ww) {
                int o = ww * 32 + t;
                float a1 = red_m1[o]; int b1 = red_k1[o];
                float a2 = red_m2[o]; int b2 = red_k2[o];
                if (a1 < M1 || (a1 == M1 && b1 < K1)) {
                    M2 = M1; K2 = K1; M1 = a1; K1 = b1;
                } else if (a1 < M2 || (a1 == M2 && b1 < K2)) { M2 = a1; K2 = b1; }
                if (a2 < M2 || (a2 == M2 && b2 < K2)) { M2 = a2; K2 = b2; }
            }
            int pick = K1;
            if (M2 - M1 <= RVQ_EPS) {
                const float* rrow = &r_lds[t * 132];
                float d1 = cbn[q * 1024 + K1] - 2.f * dot128(rrow, cbf + ((size_t)q * 1024 + K1) * 128);
                float d2 = cbn[q * 1024 + K2] - 2.f * dot128(rrow, cbf + ((size_t)q * 1024 + K2) * 128);
                if (d2 < d1 || (d2 == d1 && K2 < K1)) pick = K2;
            }
            idx_sh[t] = pick;
        }
        __syncthreads();

        // ---- update r (exact fp32) + re-split into frag buffer (row-fast)
        #pragma unroll
        for (int jj = 0; jj < 4; ++jj) {
            int f   = t + 256 * jj;
            int row = f & 31;
            int c4  = (f >> 5) << 2;
            int k   = idx_sh[row];
            float4 v = *(const float4*)(cbf + ((size_t)q * 1024 + k) * 128 + c4);
            float4* rp = (float4*)&r_lds[row * 132 + c4];
            float4 rv = *rp;
            rv.x -= v.x; rv.y -= v.y; rv.z -= v.z; rv.w -= v.w;
            *rp = rv;
            if (q < 7) {
                int nt = row >> 4, lmr = row & 15;
                int ks = c4 >> 5, lgr = (c4 >> 3) & 3, off = c4 & 7;
                int chunk = ((nt * 4 + ks) * 4 + lgr) * 16 + lmr;
                ushort4 h, l;
                split2(rv.x, h.x, l.x); split2(rv.y, h.y, l.y);
                split2(rv.z, h.z, l.z); split2(rv.w, h.w, l.w);
                *(ushort4*)&fh[chunk * 8 + off] = h;
                *(ushort4*)&fl[chunk * 8 + off] = l;
            }
        }
        __syncthreads();
    }

    // ---- zhat = z - r_final (in place, coalesced)
    #pragma unroll
    for (int jj = 0; jj < 4; ++jj) {
        int f   = t + 256 * jj;
        int row = f >> 5;
        int c4  = (f & 31) << 2;
        float4 zv = *(const float4*)(z + (size_t)(rbase + row) * 128 + c4);
        float4 rv = *(float4*)&r_lds[row * 132 + c4];
        float4 o = make_float4(zv.x - rv.x, zv.y - rv.y, zv.z - rv.z, zv.w - rv.w);
        *(float4*)(zhat + (size_t)(rbase + row) * 128 + c4) = o;
    }
}

// ---------------------------------------------------------------------------
extern "C" void kernel_launch(void* const* d_in, const int* in_sizes, int n_in,
                              void* d_out, int out_size, void* d_ws, size_t ws_size,
                              hipStream_t stream)
{
    const float* s    = (const float*)d_in[0];
    const float* goal = (const float*)d_in[1];
    const float* Wp[9]  = { (const float*)d_in[2],  (const float*)d_in[4],  (const float*)d_in[6],
                            (const float*)d_in[8],  (const float*)d_in[10], (const float*)d_in[12],
                            (const float*)d_in[14], (const float*)d_in[16], (const float*)d_in[18] };
    const float* Bp[9]  = { (const float*)d_in[3],  (const float*)d_in[5],  (const float*)d_in[7],
                            (const float*)d_in[9],  (const float*)d_in[11], (const float*)d_in[13],
                            (const float*)d_in[15], (const float*)d_in[17], (const float*)d_in[19] };
    const float* cb   = (const float*)d_in[20];
    float* out = (float*)d_out;

    static const int WK[9] = { 256, 512, 512, 384, 512, 512, 384, 1024, 1024 };
    static const int WN[9] = { 512, 512, 128, 512, 512, 128, 1024, 1024, 32 };
    size_t woff[10]; woff[0] = 0;
    for (int i = 0; i < 9; ++i) woff[i + 1] = woff[i] + (size_t)WK[i] * WN[i]; // 2457600

    float* zp  = (float*)d_ws;                       // [N,128]
    float* zz  = zp + (size_t)NROWS * 128;           // [N,128]; zhat in-place
    float* cbn = zz + (size_t)NROWS * 128;           // [8192]
    u16*  Wth  = (u16*)(cbn + 8192);
    u16*  Wtl  = Wth + woff[9];
    u16*  CBh  = Wtl + woff[9];                      // [1048576]
    u16*  CBl  = CBh + 1048576;
    uintptr_t bA = ((uintptr_t)(CBl + 1048576) + 255) & ~(uintptr_t)255;
    float* bufA = (float*)bA;

    size_t used = (size_t)(bA - (uintptr_t)d_ws);
    size_t avail = (ws_size > used) ? (ws_size - used) : 0;
    size_t ch = avail / (2 * 1024 * sizeof(float));
    if (ch > NROWS) ch = NROWS;
    ch &= ~(size_t)127;
    if (ch < 128) ch = 128;
    const int CH = (int)ch;
    float* bufB = bufA + (size_t)CH * 1024;

    dim3 blk(256);

    cbnorm_kernel<<<32, blk, 0, stream>>>(cb, cbn);
    cbsplit<<<1024, blk, 0, stream>>>(cb, CBh, CBl);
    for (int i = 0; i < 9; ++i)
        wsplit<<<dim3(WN[i] / 32, WK[i] / 64), blk, 0, stream>>>(Wp[i], Wth + woff[i], Wtl + woff[i], WK[i], WN[i]);

    // prior + posterior, chunked
    for (int off = 0; off < NROWS; off += CH) {
        int rows = (NROWS - off) < CH ? (NROWS - off) : CH;
        int gy = rows / 128;
        const float* sC = s + (size_t)off * 256;
        const float* gC = goal + (size_t)off * 128;
        gemm3<4,4,2,2,1><<<dim3(4, gy), blk, 0, stream>>>(sC, 256, nullptr, 0, Wth + woff[0], Wtl + woff[0], Bp[0], bufA, 256, 512);
        gemm3<4,4,2,2,1><<<dim3(4, gy), blk, 0, stream>>>(bufA, 512, nullptr, 0, Wth + woff[1], Wtl + woff[1], Bp[1], bufB, 512, 512);
        gemm3<4,4,2,2,0><<<dim3(1, gy), blk, 0, stream>>>(bufB, 512, nullptr, 0, Wth + woff[2], Wtl + woff[2], Bp[2], zp + (size_t)off * 128, 512, 128);
        gemm3<4,4,2,2,1><<<dim3(4, gy), blk, 0, stream>>>(sC, 256, gC, 128, Wth + woff[3], Wtl + woff[3], Bp[3], bufA, 384, 512);
        gemm3<4,4,2,2,1><<<dim3(4, gy), blk, 0, stream>>>(bufA, 512, nullptr, 0, Wth + woff[4], Wtl + woff[4], Bp[4], bufB, 512, 512);
        gemm3<4,4,2,2,0><<<dim3(1, gy), blk, 0, stream>>>(bufB, 512, nullptr, 0, Wth + woff[5], Wtl + woff[5], Bp[5], zz + (size_t)off * 128, 512, 128);
    }

    rvq_mfma<<<NROWS / 32, blk, 0, stream>>>(zz, zp, cb, CBh, CBl, cbn, zz);

    // decoder, chunked
    for (int off = 0; off < NROWS; off += CH) {
        int rows = (NROWS - off) < CH ? (NROWS - off) : CH;
        int gy = rows / 128;
        const float* sC = s + (size_t)off * 256;
        const float* zC = zz + (size_t)off * 128;
        gemm3<4,4,2,2,1><<<dim3(8, gy), blk, 0, stream>>>(sC, 256, zC, 128, Wth + woff[6], Wtl + woff[6], Bp[6], bufA, 384, 1024);
        gemm3<4,4,2,2,1><<<dim3(8, gy), blk, 0, stream>>>(bufA, 1024, nullptr, 0, Wth + woff[7], Wtl + woff[7], Bp[7], bufB, 1024, 1024);
        gemm3<2,2,1,4,0><<<dim3(1, gy), blk, 0, stream>>>(bufB, 1024, nullptr, 0, Wth + woff[8], Wtl + woff[8], Bp[8], out + (size_t)off * 32, 1024, 32);
    }
}